// Round 6
// baseline (630.618 us; speedup 1.0000x reference)
//
#include <hip/hip_runtime.h>

#define N_FINE   2000000
#define N_COARSE 500000
#define CCH      64
#define PBITS    19
#define PMASK    ((1u << PBITS) - 1u)
#define PWORDS   ((N_FINE * PBITS + 31) / 32)   // 1,187,500 words = 4.75 MB

typedef float f32x4 __attribute__((ext_vector_type(4)));
typedef unsigned short u16x8 __attribute__((ext_vector_type(8)));
typedef unsigned long long u64;

// ---------- prep 1: convert x (f32) -> bf16 (round-to-nearest-even) ----------
__global__ __launch_bounds__(256) void conv_bf16_kernel(
    const float4* __restrict__ x4, ushort4* __restrict__ xb4, int n4)
{
    int i = blockIdx.x * blockDim.x + threadIdx.x;
    if (i >= n4) return;
    float4 v = x4[i];
    union { float f; unsigned u; } a;
    ushort4 o;
    a.f = v.x; o.x = (unsigned short)((a.u + 0x7FFFu + ((a.u >> 16) & 1u)) >> 16);
    a.f = v.y; o.y = (unsigned short)((a.u + 0x7FFFu + ((a.u >> 16) & 1u)) >> 16);
    a.f = v.z; o.z = (unsigned short)((a.u + 0x7FFFu + ((a.u >> 16) & 1u)) >> 16);
    a.f = v.w; o.w = (unsigned short)((a.u + 0x7FFFu + ((a.u >> 16) & 1u)) >> 16);
    xb4[i] = o;
}

// ---------- prep 2: pack pool_map (int32) -> 19-bit entries ----------
__global__ __launch_bounds__(256) void pack_pool_kernel(
    const int* __restrict__ pool, unsigned* __restrict__ packed)
{
    int w = blockIdx.x * blockDim.x + threadIdx.x;
    if (w > PWORDS) return;
    if (w == PWORDS) { packed[w] = 0u; return; }
    int i0 = (w * 32) / PBITS;
    u64 acc = (u64)(unsigned)pool[i0];
    if (i0 + 1 < N_FINE) acc |= (u64)(unsigned)pool[i0 + 1] << PBITS;
    if (i0 + 2 < N_FINE) acc |= (u64)(unsigned)pool[i0 + 2] << (2 * PBITS);
    int sh = 32 * w - PBITS * i0;
    packed[w] = (unsigned)(acc >> sh);
}

__device__ __forceinline__ int unpack_pool(const unsigned* __restrict__ pp, int idx)
{
    int bo = idx * PBITS;
    int w  = bo >> 5;
    int s  = bo & 31;
    u64 v  = ((u64)pp[w + 1] << 32) | pp[w];
    return (int)((v >> s) & PMASK);
}

// ---------- main: 8 lanes/face, each lane = 8 channels (ushort8 = 16B) ----------
// Same 1x128B transaction per row-tap as before, but 2x faces/wave (more MLP),
// half the VALU/index overhead per byte, and all 9 gathers batched in flight.
__global__ __launch_bounds__(256) void smooth_upsample_bf16_ilp(
    const ushort*   __restrict__ xb,   // [N_COARSE, 64] bf16
    const unsigned* __restrict__ pp,   // packed pool_map, 19b/entry
    const int*      __restrict__ nbr,  // [N_FINE, 9]
    float*          __restrict__ out)  // [N_FINE, 64]
{
    const int tid = blockIdx.x * blockDim.x + threadIdx.x;
    const int f   = tid >> 3;
    const int c8  = tid & 7;
    if (f >= N_FINE) return;

    const float W[9] = {0.25f, 0.125f, 0.0625f, 0.125f, 0.0625f,
                        0.125f, 0.0625f, 0.125f, 0.0625f};

    const int* nrow = nbr + f * 9;

    // batch 1: all neighbor indices
    int nb[9];
#pragma unroll
    for (int i = 0; i < 9; ++i) nb[i] = (i == 0) ? f : nrow[i];

    // batch 2: validity + packed-pool gathers (pp is ~L2-resident)
    float w[9];
    int   pm[9];
#pragma unroll
    for (int i = 0; i < 9; ++i) {
        bool valid = (nb[i] != N_FINE);
        w[i]  = valid ? W[i] : 0.f;
        pm[i] = unpack_pool(pp, valid ? nb[i] : 0);
    }

    // batch 3: all 9 row gathers in flight (16B per lane, 128B per row)
    u16x8 v[9];
#pragma unroll
    for (int i = 0; i < 9; ++i)
        v[i] = *reinterpret_cast<const u16x8*>(xb + (size_t)pm[i] * CCH + c8 * 8);

    // batch 4: accumulate
    float acc[8] = {0.f, 0.f, 0.f, 0.f, 0.f, 0.f, 0.f, 0.f};
    float corr = 0.f;
#pragma unroll
    for (int i = 0; i < 9; ++i) {
        corr += w[i];
#pragma unroll
        for (int j = 0; j < 8; ++j)
            acc[j] = fmaf(w[i], __uint_as_float((unsigned)v[i][j] << 16), acc[j]);
    }

    const float inv = 1.0f / corr;
    f32x4 o0, o1;
    o0.x = acc[0] * inv; o0.y = acc[1] * inv; o0.z = acc[2] * inv; o0.w = acc[3] * inv;
    o1.x = acc[4] * inv; o1.y = acc[5] * inv; o1.z = acc[6] * inv; o1.w = acc[7] * inv;

    f32x4* dst = reinterpret_cast<f32x4*>(out) + tid * 2;  // (f*64 + c8*8)*4B
    __builtin_nontemporal_store(o0, dst);
    __builtin_nontemporal_store(o1, dst + 1);
}

// ---------- fallback (f32 gathers) if workspace too small ----------
__global__ __launch_bounds__(256) void smooth_upsample_f32(
    const float* __restrict__ x,
    const int*   __restrict__ nbr,
    const int*   __restrict__ pool_map,
    float*       __restrict__ out)
{
    const int tid = blockIdx.x * blockDim.x + threadIdx.x;
    const int f   = tid >> 4;
    const int c4  = tid & 15;
    if (f >= N_FINE) return;

    const float W[9] = {0.25f, 0.125f, 0.0625f, 0.125f, 0.0625f,
                        0.125f, 0.0625f, 0.125f, 0.0625f};
    const int* nrow = nbr + f * 9;
    float4 acc = make_float4(0.f, 0.f, 0.f, 0.f);
    float  corr = 0.f;
#pragma unroll
    for (int i = 0; i < 9; ++i) {
        int  nb    = nrow[i];
        bool valid = (nb != N_FINE);
        int  nbc   = valid ? nb : 0;
        int  pm    = pool_map[nbc];
        const float4* row = reinterpret_cast<const float4*>(x + (size_t)pm * CCH);
        float4 v = row[c4];
        float  ww = valid ? W[i] : 0.f;
        acc.x = fmaf(ww, v.x, acc.x);
        acc.y = fmaf(ww, v.y, acc.y);
        acc.z = fmaf(ww, v.z, acc.z);
        acc.w = fmaf(ww, v.w, acc.w);
        corr += ww;
    }
    const float inv = 1.0f / corr;
    f32x4 o;
    o.x = acc.x * inv; o.y = acc.y * inv; o.z = acc.z * inv; o.w = acc.w * inv;
    __builtin_nontemporal_store(o, reinterpret_cast<f32x4*>(out) + tid);
}

extern "C" void kernel_launch(void* const* d_in, const int* in_sizes, int n_in,
                              void* d_out, int out_size, void* d_ws, size_t ws_size,
                              hipStream_t stream) {
    const float* x        = (const float*)d_in[0];
    const int*   nbr      = (const int*)d_in[1];
    const int*   pool_map = (const int*)d_in[4];
    float*       out      = (float*)d_out;

    const size_t xb_bytes = (size_t)N_COARSE * CCH * sizeof(unsigned short); // 64 MB
    const size_t pp_bytes = (size_t)(PWORDS + 1) * sizeof(unsigned);         // ~4.75 MB

    if (ws_size >= xb_bytes + pp_bytes) {
        ushort*   xb = (ushort*)d_ws;
        unsigned* pp = (unsigned*)((char*)d_ws + xb_bytes);

        const int n4 = N_COARSE * CCH / 4;  // 8M float4 groups
        conv_bf16_kernel<<<(n4 + 255) / 256, 256, 0, stream>>>(
            (const float4*)x, (ushort4*)xb, n4);
        pack_pool_kernel<<<(PWORDS + 1 + 255) / 256, 256, 0, stream>>>(pool_map, pp);

        const long long total_threads = (long long)N_FINE * 8;  // 16M
        const int block = 256;
        const int grid  = (int)((total_threads + block - 1) / block);  // 62500
        smooth_upsample_bf16_ilp<<<grid, block, 0, stream>>>(xb, pp, nbr, out);
    } else {
        const long long total_threads = (long long)N_FINE * 16;
        const int block = 256;
        const int grid  = (int)((total_threads + block - 1) / block);
        smooth_upsample_f32<<<grid, block, 0, stream>>>(x, nbr, pool_map, out);
    }
}